// Round 1
// baseline (2798.857 us; speedup 1.0000x reference)
//
#include <hip/hip_runtime.h>
#include <math.h>

#define CDIM 96
#define NHEADS 8
#define HDIM 12
#define HID 384
#define BB 8
#define HLR 96
#define WLR 96
#define HH 192
#define WW 192
#define NTOK (HH*WW)            // 36864
#define TTOT (BB*NTOK)          // 294912
#define PB 256                  // blocks per batch for k2 kernels
#define NPB (NTOK/PB)           // 144 tokens per block

__device__ __forceinline__ float gelu_(float x){
    return 0.5f * x * (1.0f + erff(x * 0.70710678118654752f));
}

__device__ __forceinline__ void atomicMaxF(float* addr, float v){
    if (v >= 0.0f) atomicMax((int*)addr, __float_as_int(v));
    else           atomicMin((unsigned int*)addr, __float_as_uint(v));
}

// ---------------- init accumulators ----------------
__global__ void k_init(float* kmax, float* ksum, float* ctx_un){
    int i = blockIdx.x*256 + threadIdx.x;
    if (i < BB*CDIM){ kmax[i] = -1e30f; ksum[i] = 0.0f; }
    if (i < BB*CDIM*HDIM) ctx_un[i] = 0.0f;
}

// ---------------- K1: upsample + coord-enc + MLP1 + LN1 ----------------
__global__ __launch_bounds__(256) void k1_mlp1(
    const float* __restrict__ feat, const float* __restrict__ w1, const float* __restrict__ b1,
    const float* __restrict__ w2, const float* __restrict__ b2,
    const float* __restrict__ g1, const float* __restrict__ be1, float* __restrict__ x1)
{
    const int tid = threadIdx.x, wid = tid>>6, lane = tid&63;
    const bool h2 = lane < 32;
    __shared__ float comb[4][4][192];
    __shared__ float hid[4][4][HID];
    const int tbase = blockIdx.x*16 + wid*4;

    for (int tt=0; tt<4; ++tt){
        int t = tbase+tt;
        int b = t / NTOK, n = t % NTOK;
        int row = n / WW, col = n % WW;
        float fy = (row+0.5f)*0.5f - 0.5f;    // HLR/HH = 0.5
        float fx = (col+0.5f)*0.5f - 0.5f;
        int y0 = (int)floorf(fy), x0 = (int)floorf(fx);
        float dy = fy - (float)y0, dx = fx - (float)x0;
        int y0c = min(max(y0,0),HLR-1), y1c = min(max(y0+1,0),HLR-1);
        int x0c = min(max(x0,0),WLR-1), x1c = min(max(x0+1,0),WLR-1);
        float w00=(1.f-dy)*(1.f-dx), w01=(1.f-dy)*dx, w10=dy*(1.f-dx), w11=dy*dx;
        float yn = (float)row/(float)(HH-1), xn = (float)col/(float)(WW-1);
        float c0 = yn*1.0f, c1 = xn*1.0f;     // cs = 2/scale = 1
        for (int c=lane; c<192; c+=64){
            float v;
            if (c < CDIM){
                const float* fp = feat + ((size_t)(b*CDIM + c)*HLR)*WLR;
                v = w00*fp[y0c*WLR+x0c] + w01*fp[y0c*WLR+x1c]
                  + w10*fp[y1c*WLR+x0c] + w11*fp[y1c*WLR+x1c];
            } else {
                int cc = c - CDIM;
                int fi = cc >> 3, r = cc & 7, coord = r >> 1;
                float cv = (coord==0)? c0 : (coord==1)? c1 : (coord==2)? yn : xn;
                float ph = cv * ((float)(1<<fi) * 3.14159265358979323846f);
                v = (r & 1) ? cosf(ph) : sinf(ph);
            }
            comb[wid][tt][c] = v;
        }
    }
    __syncthreads();

    // hidden = gelu(combined @ w1 + b1)
    float acc[4][6];
    #pragma unroll
    for (int r=0;r<6;++r){
        float bb = b1[lane+64*r];
        #pragma unroll
        for (int tt=0;tt<4;++tt) acc[tt][r] = bb;
    }
    for (int i=0;i<192;++i){
        float wr[6];
        #pragma unroll
        for (int r=0;r<6;++r) wr[r] = w1[i*HID + lane + 64*r];
        #pragma unroll
        for (int tt=0;tt<4;++tt){
            float cv = comb[wid][tt][i];
            #pragma unroll
            for (int r=0;r<6;++r) acc[tt][r] += cv*wr[r];
        }
    }
    #pragma unroll
    for (int tt=0;tt<4;++tt)
        #pragma unroll
        for (int r=0;r<6;++r)
            hid[wid][tt][lane+64*r] = gelu_(acc[tt][r]);
    __syncthreads();

    // out = hidden @ w2 + b2, then LN1
    float oa0[4], oa1[4];
    {
        float bb0 = b2[lane], bb1 = h2 ? b2[64+lane] : 0.0f;
        #pragma unroll
        for (int tt=0;tt<4;++tt){ oa0[tt]=bb0; oa1[tt]=bb1; }
    }
    for (int i=0;i<HID;++i){
        float w0v = w2[i*CDIM + lane];
        float w1v = h2 ? w2[i*CDIM + 64 + lane] : 0.0f;
        #pragma unroll
        for (int tt=0;tt<4;++tt){
            float hv = hid[wid][tt][i];
            oa0[tt] += hv*w0v; oa1[tt] += hv*w1v;
        }
    }
    float ga = g1[lane], bea = be1[lane];
    float gb = h2 ? g1[64+lane] : 0.0f, beb = h2 ? be1[64+lane] : 0.0f;
    for (int tt=0;tt<4;++tt){
        float s  = oa0[tt] + (h2 ? oa1[tt] : 0.0f);
        float sq = oa0[tt]*oa0[tt] + (h2 ? oa1[tt]*oa1[tt] : 0.0f);
        #pragma unroll
        for (int m=32;m;m>>=1){ s += __shfl_xor(s,m); sq += __shfl_xor(sq,m); }
        float mean = s*(1.0f/CDIM);
        float var  = sq*(1.0f/CDIM) - mean*mean;
        float rstd = rsqrtf(var + 1e-5f);
        size_t t = (size_t)(tbase+tt);
        x1[t*CDIM + lane] = (oa0[tt]-mean)*rstd*ga + bea;
        if (h2) x1[t*CDIM + 64 + lane] = (oa1[tt]-mean)*rstd*gb + beb;
    }
}

// ---------------- K2a: per-(b,h,d) max of k over tokens ----------------
__global__ __launch_bounds__(256) void k2a_kmax(
    const float* __restrict__ x1, const float* __restrict__ qkvw, float* __restrict__ kmax)
{
    const int tid = threadIdx.x, wid = tid>>6, lane = tid&63;
    const bool h2 = lane < 32;
    const int b = blockIdx.x / PB, pb = blockIdx.x % PB;
    __shared__ float xsh[4][4][CDIM];
    __shared__ float wm[4][CDIM];
    float m0 = -1e30f, m1 = -1e30f;

    for (int it=0; it<NPB/16; ++it){
        int nb = pb*NPB + it*16 + wid*4;
        for (int tt=0;tt<4;++tt){
            size_t t = (size_t)b*NTOK + nb + tt;
            xsh[wid][tt][lane] = x1[t*CDIM + lane];
            if (h2) xsh[wid][tt][64+lane] = x1[t*CDIM + 64 + lane];
        }
        __syncthreads();
        float a0[4]={0,0,0,0}, a1[4]={0,0,0,0};
        for (int c=0;c<CDIM;++c){
            float wv0 = qkvw[c*288 + 96 + lane];
            float wv1 = h2 ? qkvw[c*288 + 160 + lane] : 0.0f;
            #pragma unroll
            for (int tt=0;tt<4;++tt){
                float xv = xsh[wid][tt][c];
                a0[tt] += xv*wv0; a1[tt] += xv*wv1;
            }
        }
        #pragma unroll
        for (int tt=0;tt<4;++tt){ m0 = fmaxf(m0,a0[tt]); m1 = fmaxf(m1,a1[tt]); }
        __syncthreads();
    }
    wm[wid][lane] = m0;
    if (h2) wm[wid][64+lane] = m1;
    __syncthreads();
    if (tid < CDIM){
        float m = fmaxf(fmaxf(wm[0][tid],wm[1][tid]), fmaxf(wm[2][tid],wm[3][tid]));
        atomicMaxF(&kmax[b*CDIM + tid], m);
    }
}

// ---------------- K2b: ksum + unnormalized ctx ----------------
__global__ __launch_bounds__(256) void k2b_ctx(
    const float* __restrict__ x1, const float* __restrict__ qkvw,
    const float* __restrict__ kmax, float* __restrict__ ksum, float* __restrict__ ctx_un)
{
    const int tid = threadIdx.x, wid = tid>>6, lane = tid&63;
    const bool h2 = lane < 32;
    const int b = blockIdx.x / PB, pb = blockIdx.x % PB;
    __shared__ float xsh[4][4][CDIM];
    __shared__ float esh[4][4][CDIM];
    __shared__ float vsh[4][4][CDIM];
    __shared__ float cp[4][CDIM*HDIM];   // per-wave ctx partial
    __shared__ float ssh[4][CDIM];
    for (int i=tid; i<4*CDIM*HDIM; i+=256) (&cp[0][0])[i] = 0.0f;
    __syncthreads();

    float km0 = kmax[b*CDIM + lane];
    float km1 = h2 ? kmax[b*CDIM + 64 + lane] : 0.0f;
    float rs0 = 0.0f, rs1 = 0.0f;

    for (int it=0; it<NPB/16; ++it){
        int nb = pb*NPB + it*16 + wid*4;
        for (int tt=0;tt<4;++tt){
            size_t t = (size_t)b*NTOK + nb + tt;
            xsh[wid][tt][lane] = x1[t*CDIM + lane];
            if (h2) xsh[wid][tt][64+lane] = x1[t*CDIM + 64 + lane];
        }
        __syncthreads();
        float ka0[4]={0,0,0,0}, ka1[4]={0,0,0,0}, va0[4]={0,0,0,0}, va1[4]={0,0,0,0};
        for (int c=0;c<CDIM;++c){
            float wk0 = qkvw[c*288 + 96 + lane];
            float wk1 = h2 ? qkvw[c*288 + 160 + lane] : 0.0f;
            float wv0 = qkvw[c*288 + 192 + lane];
            float wv1 = h2 ? qkvw[c*288 + 256 + lane] : 0.0f;
            #pragma unroll
            for (int tt=0;tt<4;++tt){
                float xv = xsh[wid][tt][c];
                ka0[tt] += xv*wk0; ka1[tt] += xv*wk1;
                va0[tt] += xv*wv0; va1[tt] += xv*wv1;
            }
        }
        for (int tt=0;tt<4;++tt){
            float e0 = expf(ka0[tt]-km0);
            esh[wid][tt][lane] = e0; vsh[wid][tt][lane] = va0[tt];
            rs0 += e0;
            if (h2){
                float e1 = expf(ka1[tt]-km1);
                esh[wid][tt][64+lane] = e1; vsh[wid][tt][64+lane] = va1[tt];
                rs1 += e1;
            }
        }
        __syncthreads();
        for (int tt=0;tt<4;++tt){
            #pragma unroll
            for (int idx=lane; idx<CDIM*HDIM; idx+=64){
                int j  = idx / HDIM;           // h*12+d
                int ee = idx % HDIM;
                int h  = idx / (HDIM*HDIM);
                cp[wid][idx] += esh[wid][tt][j] * vsh[wid][tt][h*HDIM + ee];
            }
        }
        __syncthreads();
    }
    ssh[wid][lane] = rs0;
    if (h2) ssh[wid][64+lane] = rs1;
    __syncthreads();
    if (tid < CDIM)
        atomicAdd(&ksum[b*CDIM + tid], ssh[0][tid]+ssh[1][tid]+ssh[2][tid]+ssh[3][tid]);
    for (int idx=tid; idx<CDIM*HDIM; idx+=256)
        atomicAdd(&ctx_un[b*CDIM*HDIM + idx], cp[0][idx]+cp[1][idx]+cp[2][idx]+cp[3][idx]);
}

// ---------------- K2c: normalize ctx ----------------
__global__ void k2c_norm(const float* __restrict__ ctx_un, const float* __restrict__ ksum,
                         float* __restrict__ ctxn){
    int i = blockIdx.x*256 + threadIdx.x;
    if (i < BB*CDIM*HDIM){
        int b = i / (CDIM*HDIM);
        int j = (i % (CDIM*HDIM)) / HDIM;
        ctxn[i] = ctx_un[i] / ksum[b*CDIM + j];
    }
}

// ---------------- K3: q + attn + proj + LN2 + MLP2 + output ----------------
__global__ __launch_bounds__(256) void k3_out(
    const float* __restrict__ x1, const float* __restrict__ qkvw, const float* __restrict__ ctxn,
    const float* __restrict__ projw, const float* __restrict__ projb,
    const float* __restrict__ g2, const float* __restrict__ be2,
    const float* __restrict__ m2w1, const float* __restrict__ m2b1,
    const float* __restrict__ m2w2, const float* __restrict__ m2b2,
    float* __restrict__ out)
{
    const int tid = threadIdx.x, wid = tid>>6, lane = tid&63;
    const bool h2 = lane < 32;
    const int tbase = blockIdx.x*16 + wid*4;
    const int b = (blockIdx.x*16) / NTOK;     // NTOK % 16 == 0, uniform per block
    __shared__ float ctx_sh[CDIM*HDIM];
    __shared__ float xsh[4][4][CDIM];
    __shared__ float qsh[4][4][CDIM];
    __shared__ float ash[4][4][CDIM];
    __shared__ float x2sh[4][4][CDIM];
    __shared__ float hsh[4][4][HID];

    for (int i=tid; i<CDIM*HDIM; i+=256) ctx_sh[i] = ctxn[b*CDIM*HDIM + i];
    for (int tt=0;tt<4;++tt){
        size_t t = (size_t)(tbase+tt);
        xsh[wid][tt][lane] = x1[t*CDIM + lane];
        if (h2) xsh[wid][tt][64+lane] = x1[t*CDIM + 64 + lane];
    }
    __syncthreads();

    // q (raw)
    float qa0[4]={0,0,0,0}, qa1[4]={0,0,0,0};
    for (int c=0;c<CDIM;++c){
        float w0v = qkvw[c*288 + lane];
        float w1v = h2 ? qkvw[c*288 + 64 + lane] : 0.0f;
        #pragma unroll
        for (int tt=0;tt<4;++tt){
            float xv = xsh[wid][tt][c];
            qa0[tt] += xv*w0v; qa1[tt] += xv*w1v;
        }
    }
    for (int tt=0;tt<4;++tt){
        qsh[wid][tt][lane] = qa0[tt];
        if (h2) qsh[wid][tt][64+lane] = qa1[tt];
    }
    __syncthreads();

    // attn = softmax(q,hd)*hd^-0.5 @ ctx
    const float scl = 0.28867513459481287f;   // 12^-0.5
    for (int tt=0;tt<4;++tt){
        {
            int j = lane, h = j/HDIM, ee = j%HDIM;
            float qs[12];
            #pragma unroll
            for (int d=0;d<12;++d) qs[d] = qsh[wid][tt][h*HDIM+d];
            float m = qs[0];
            #pragma unroll
            for (int d=1;d<12;++d) m = fmaxf(m,qs[d]);
            float s=0.0f, a=0.0f;
            #pragma unroll
            for (int d=0;d<12;++d){
                float e = expf(qs[d]-m);
                s += e; a += e*ctx_sh[(h*HDIM+d)*HDIM + ee];
            }
            ash[wid][tt][j] = a/s*scl;
        }
        if (h2){
            int j = 64+lane, h = j/HDIM, ee = j%HDIM;
            float qs[12];
            #pragma unroll
            for (int d=0;d<12;++d) qs[d] = qsh[wid][tt][h*HDIM+d];
            float m = qs[0];
            #pragma unroll
            for (int d=1;d<12;++d) m = fmaxf(m,qs[d]);
            float s=0.0f, a=0.0f;
            #pragma unroll
            for (int d=0;d<12;++d){
                float e = expf(qs[d]-m);
                s += e; a += e*ctx_sh[(h*HDIM+d)*HDIM + ee];
            }
            ash[wid][tt][j] = a/s*scl;
        }
    }
    __syncthreads();

    // proj + residual + LN2
    float pa0[4], pa1[4];
    {
        float pb0 = projb[lane], pb1 = h2 ? projb[64+lane] : 0.0f;
        #pragma unroll
        for (int tt=0;tt<4;++tt){ pa0[tt]=pb0; pa1[tt]=pb1; }
    }
    for (int c=0;c<CDIM;++c){
        float w0v = projw[c*CDIM + lane];
        float w1v = h2 ? projw[c*CDIM + 64 + lane] : 0.0f;
        #pragma unroll
        for (int tt=0;tt<4;++tt){
            float av = ash[wid][tt][c];
            pa0[tt] += av*w0v; pa1[tt] += av*w1v;
        }
    }
    float ga = g2[lane], bea = be2[lane];
    float gb = h2 ? g2[64+lane] : 0.0f, beb = h2 ? be2[64+lane] : 0.0f;
    for (int tt=0;tt<4;++tt){
        float v0 = xsh[wid][tt][lane] + pa0[tt];
        float v1 = h2 ? (xsh[wid][tt][64+lane] + pa1[tt]) : 0.0f;
        float s = v0+v1, sq = v0*v0+v1*v1;
        #pragma unroll
        for (int m=32;m;m>>=1){ s += __shfl_xor(s,m); sq += __shfl_xor(sq,m); }
        float mean = s*(1.0f/CDIM);
        float var  = sq*(1.0f/CDIM) - mean*mean;
        float rstd = rsqrtf(var + 1e-5f);
        x2sh[wid][tt][lane] = (v0-mean)*rstd*ga + bea;
        if (h2) x2sh[wid][tt][64+lane] = (v1-mean)*rstd*gb + beb;
    }
    __syncthreads();

    // MLP2 hidden
    float ha[4][6];
    #pragma unroll
    for (int r=0;r<6;++r){
        float bb = m2b1[lane+64*r];
        #pragma unroll
        for (int tt=0;tt<4;++tt) ha[tt][r] = bb;
    }
    for (int c=0;c<CDIM;++c){
        float wr[6];
        #pragma unroll
        for (int r=0;r<6;++r) wr[r] = m2w1[c*HID + lane + 64*r];
        #pragma unroll
        for (int tt=0;tt<4;++tt){
            float xv = x2sh[wid][tt][c];
            #pragma unroll
            for (int r=0;r<6;++r) ha[tt][r] += xv*wr[r];
        }
    }
    #pragma unroll
    for (int tt=0;tt<4;++tt)
        #pragma unroll
        for (int r=0;r<6;++r)
            hsh[wid][tt][lane+64*r] = gelu_(ha[tt][r]);
    __syncthreads();

    // rgb
    for (int tt=0;tt<4;++tt){
        int t = tbase+tt;
        int n = t % NTOK, row = n/WW, col = n%WW;
        float p0=0.f, p1=0.f, p2=0.f;
        for (int i=lane;i<HID;i+=64){
            float hv = hsh[wid][tt][i];
            p0 += hv*m2w2[i*3+0]; p1 += hv*m2w2[i*3+1]; p2 += hv*m2w2[i*3+2];
        }
        #pragma unroll
        for (int m=32;m;m>>=1){
            p0 += __shfl_xor(p0,m); p1 += __shfl_xor(p1,m); p2 += __shfl_xor(p2,m);
        }
        if (lane < 3){
            float pv = (lane==0) ? p0 : (lane==1) ? p1 : p2;
            float v = tanhf(pv + m2b2[lane])*0.5f + 0.5f;
            v = fminf(fmaxf(v, 0.0f), 1.0f);
            out[((size_t)(b*3+lane)*HH + row)*WW + col] = v;
        }
    }
}

extern "C" void kernel_launch(void* const* d_in, const int* in_sizes, int n_in,
                              void* d_out, int out_size, void* d_ws, size_t ws_size,
                              hipStream_t stream)
{
    const float* feat  = (const float*)d_in[0];
    // d_in[1] = scale (int, ==2), baked into constants
    const float* m1w1  = (const float*)d_in[2];
    const float* m1b1  = (const float*)d_in[3];
    const float* m1w2  = (const float*)d_in[4];
    const float* m1b2  = (const float*)d_in[5];
    const float* n1g   = (const float*)d_in[6];
    const float* n1b   = (const float*)d_in[7];
    const float* qkvw  = (const float*)d_in[8];
    const float* projw = (const float*)d_in[9];
    const float* projb = (const float*)d_in[10];
    const float* n2g   = (const float*)d_in[11];
    const float* n2b   = (const float*)d_in[12];
    const float* m2w1  = (const float*)d_in[13];
    const float* m2b1  = (const float*)d_in[14];
    const float* m2w2  = (const float*)d_in[15];
    const float* m2b2  = (const float*)d_in[16];
    float* out = (float*)d_out;

    float* x1     = (float*)d_ws;                      // TTOT*96 floats
    float* kmax   = x1 + (size_t)TTOT*CDIM;
    float* ksum   = kmax + BB*CDIM;
    float* ctx_un = ksum + BB*CDIM;
    float* ctxn   = ctx_un + BB*CDIM*HDIM;

    hipLaunchKernelGGL(k_init, dim3(36), dim3(256), 0, stream, kmax, ksum, ctx_un);
    hipLaunchKernelGGL(k1_mlp1, dim3(TTOT/16), dim3(256), 0, stream,
                       feat, m1w1, m1b1, m1w2, m1b2, n1g, n1b, x1);
    hipLaunchKernelGGL(k2a_kmax, dim3(BB*PB), dim3(256), 0, stream, x1, qkvw, kmax);
    hipLaunchKernelGGL(k2b_ctx, dim3(BB*PB), dim3(256), 0, stream, x1, qkvw, kmax, ksum, ctx_un);
    hipLaunchKernelGGL(k2c_norm, dim3(36), dim3(256), 0, stream, ctx_un, ksum, ctxn);
    hipLaunchKernelGGL(k3_out, dim3(TTOT/16), dim3(256), 0, stream,
                       x1, qkvw, ctxn, projw, projb, n2g, n2b, m2w1, m2b1, m2w2, m2b2, out);
}

// Round 3
// 743.214 us; speedup vs baseline: 3.7659x; 3.7659x over previous
//
#include <hip/hip_runtime.h>
#include <math.h>

typedef unsigned short u16;
typedef unsigned int   u32;
typedef __bf16  bf16x8 __attribute__((ext_vector_type(8)));
typedef short   s16x8  __attribute__((ext_vector_type(8)));
typedef float   f32x4  __attribute__((ext_vector_type(4)));

#define NTOK 36864
#define TTOT (8*NTOK)

__device__ __forceinline__ f32x4 mfma16(s16x8 a, s16x8 b, f32x4 c){
  return __builtin_amdgcn_mfma_f32_16x16x32_bf16(
      __builtin_bit_cast(bf16x8, a), __builtin_bit_cast(bf16x8, b), c, 0, 0, 0);
}
// NOTE: only valid for stride % 128 == 0 (XOR touches bits 4-6 -> bijective
// within each aligned 128B block). stride 192 was the round-2 bug.
__device__ __forceinline__ int swz(int row, int bc, int stride){
  return row*stride + (bc ^ ((row&7)<<4));
}
__device__ __forceinline__ u16 f2bf(float f){
  u32 u = __float_as_uint(f);
  return (u16)((u + 0x7fffu + ((u>>16)&1u)) >> 16);
}
__device__ __forceinline__ float bf2f(u16 h){ return __uint_as_float(((u32)h)<<16); }

// A&S 7.1.26 erf (|err|<1.5e-7)
__device__ __forceinline__ float gelu_(float x){
  float z = fabsf(x) * 0.70710678118654752f;
  float t = 1.0f/(1.0f + 0.3275911f*z);
  float poly = t*(0.254829592f + t*(-0.284496736f + t*(1.421413741f + t*(-1.453152027f + t*1.061405429f))));
  float e = __expf(-z*z);
  float erf = 1.0f - poly*e;
  erf = (x < 0.0f) ? -erf : erf;
  return 0.5f*x*(1.0f + erf);
}
__device__ __forceinline__ float tanhf_(float x){
  float e = __expf(2.0f*x);
  return 1.0f - 2.0f/(e + 1.0f);
}

#define LDSF(arr, row, kc, stride) (*(const s16x8*)((const char*)(arr) + swz((row),(kc)*2,(stride))))

// ---------------- prep: weights -> bf16 transposed ----------------
__global__ void prep_w(const float* __restrict__ w1, const float* __restrict__ w2,
                       const float* __restrict__ qkvw, const float* __restrict__ projw,
                       const float* __restrict__ m2w1, const float* __restrict__ m2w2,
                       u16* __restrict__ w1t, u16* __restrict__ w2t,
                       u16* __restrict__ wqt, u16* __restrict__ wkt, u16* __restrict__ wvt,
                       u16* __restrict__ pjt, u16* __restrict__ m2w1t, u16* __restrict__ m2w2t)
{
  int i = blockIdx.x*256 + threadIdx.x;
  if (i < 73728){ int n=i/192, k=i%192; w1t[i] = f2bf(w1[k*384+n]); return; }
  i -= 73728;
  if (i < 36864){ int n=i/384, k=i%384; w2t[i] = f2bf(w2[k*96+n]); return; }
  i -= 36864;
  if (i < 9216){ int n=i/96, k=i%96; wqt[i] = f2bf(qkvw[k*288+n]); return; }
  i -= 9216;
  if (i < 9216){ int n=i/96, k=i%96; wkt[i] = f2bf(qkvw[k*288+96+n]); return; }
  i -= 9216;
  if (i < 9216){ int n=i/96, k=i%96; wvt[i] = f2bf(qkvw[k*288+192+n]); return; }
  i -= 9216;
  if (i < 9216){ int n=i/96, k=i%96; pjt[i] = f2bf(projw[k*96+n]); return; }
  i -= 9216;
  if (i < 36864){ int n=i/96, k=i%96; m2w1t[i] = f2bf(m2w1[k*384+n]); return; }
  i -= 36864;
  if (i < 6144){ int n=i/384, k=i%384; m2w2t[i] = (n<3)? f2bf(m2w2[k*3+n]) : (u16)0; return; }
}

// ---------------- prep: features -> channel-last bf16 ----------------
__global__ void prep_feat(const float* __restrict__ feat, u16* __restrict__ featcl){
  __shared__ u16 t[96*100];
  const int tid = threadIdx.x;
  const int b = blockIdx.x/96, y = blockIdx.x%96;
  for (int i=tid; i<9216; i+=256){
    int c = i/96, x = i%96;
    t[c*100+x] = f2bf(feat[((size_t)(b*96+c)*96 + y)*96 + x]);
  }
  __syncthreads();
  for (int i=tid; i<9216; i+=256){
    int x = i/96, c = i%96;
    featcl[(((size_t)b*96 + y)*96 + x)*96 + c] = t[c*100+x];
  }
}

// ---------------- prep: coord encoding (scale==2 -> cs==1) ----------------
__global__ void prep_ce(u16* __restrict__ ce){
  int gid = blockIdx.x*256 + threadIdx.x;
  if (gid >= 36864*48) return;
  int n = gid/48, c2 = gid%48;
  int row = n/192, col = n%192;
  int fi = c2>>2, cs = c2&3;
  float coord = ((cs&1)==0) ? (float)row*(1.0f/191.0f) : (float)col*(1.0f/191.0f);
  float u = coord * (float)(1<<fi);
  u = u - 2.0f*floorf(u*0.5f);
  float ph = u * 3.14159265358979323846f;
  float s, c;
  __sincosf(ph, &s, &c);
  u32 pk = (u32)f2bf(s) | ((u32)f2bf(c)<<16);
  *(u32*)(ce + (size_t)n*96 + c2*2) = pk;
}

// ---------------- K1: upsample+ce -> MLP1 -> LN1 -> x1(bf16) ----------------
__global__ __launch_bounds__(256,2) void k1(
    const u16* __restrict__ featcl, const u16* __restrict__ ce,
    const u16* __restrict__ w1t, const float* __restrict__ b1,
    const u16* __restrict__ w2t, const float* __restrict__ b2,
    const float* __restrict__ g1, const float* __restrict__ be1,
    u16* __restrict__ x1)
{
  __shared__ u16 comb[64*192];    // stride 384B swz; reused stride 256B for x1 staging
  __shared__ u16 hidsh[64*384];   // stride 768B swz
  __shared__ float gwy[8][2]; __shared__ int giy[8][2];
  __shared__ float gwx[8][2]; __shared__ int gix[8][2];
  const int tid = threadIdx.x, w = tid>>6, lane = tid&63, kg = lane>>4, ln = lane&15;
  const int bi = blockIdx.x;
  const int b = bi/576, rem = bi%576, ty = rem/24, tx = rem%24;

  if (tid < 8){
    int row = ty*8 + tid;
    float fy = row*0.5f - 0.25f;
    int y0 = (int)floorf(fy); float dy = fy - (float)y0;
    giy[tid][0] = max(y0,0); giy[tid][1] = min(y0+1,95);
    gwy[tid][0] = 1.f-dy;    gwy[tid][1] = dy;
  } else if (tid < 16){
    int t = tid-8;
    int col = tx*8 + t;
    float fx = col*0.5f - 0.25f;
    int x0 = (int)floorf(fx); float dx = fx - (float)x0;
    gix[t][0] = max(x0,0); gix[t][1] = min(x0+1,95);
    gwx[t][0] = 1.f-dx;    gwx[t][1] = dx;
  }
  __syncthreads();

  // bilinear features -> comb[:, 0:96]
  const u16* fbase = featcl + (size_t)b*884736;
  for (int i=tid; i<64*48; i+=256){
    int l = i/48, c2 = i%48;
    int ly = l>>3, lx = l&7;
    float a0=0.f, a1=0.f;
    #pragma unroll
    for (int yy=0; yy<2; ++yy){
      #pragma unroll
      for (int xx=0; xx<2; ++xx){
        u32 u = *(const u32*)(fbase + ((size_t)(giy[ly][yy]*96 + gix[lx][xx]))*96 + c2*2);
        float wgt = gwy[ly][yy]*gwx[lx][xx];
        a0 += wgt * bf2f((u16)(u&0xffffu));
        a1 += wgt * bf2f((u16)(u>>16));
      }
    }
    u32 pk = (u32)f2bf(a0) | ((u32)f2bf(a1)<<16);
    *(u32*)((char*)comb + swz(l, c2*4, 384)) = pk;
  }
  // ce -> comb[:, 96:192]
  for (int i=tid; i<64*12; i+=256){
    int l = i/12, sg = i%12;
    int n = (ty*8+(l>>3))*192 + tx*8 + (l&7);
    *(s16x8*)((char*)comb + swz(l, 192 + sg*16, 384)) = *(const s16x8*)(ce + (size_t)n*96 + sg*8);
  }
  __syncthreads();

  // gemm1: [64,192]x[192,384], wave w -> cols 96w..96w+95
  f32x4 acc[4][6] = {};
  #pragma unroll
  for (int ks=0; ks<6; ++ks){
    s16x8 af[4];
    #pragma unroll
    for (int mf=0; mf<4; ++mf) af[mf] = LDSF(comb, 16*mf+ln, ks*32+8*kg, 384);
    #pragma unroll
    for (int nf=0; nf<6; ++nf){
      s16x8 bfr = *(const s16x8*)(w1t + (size_t)(96*w+16*nf+ln)*192 + ks*32+8*kg);
      #pragma unroll
      for (int mf=0; mf<4; ++mf) acc[mf][nf] = mfma16(af[mf], bfr, acc[mf][nf]);
    }
  }
  // gelu -> hidden bf16
  #pragma unroll
  for (int nf=0; nf<6; ++nf){
    int col = 96*w + 16*nf + ln;
    float bias = b1[col];
    #pragma unroll
    for (int mf=0; mf<4; ++mf){
      #pragma unroll
      for (int r=0; r<4; ++r){
        float v = gelu_(acc[mf][nf][r] + bias);
        *(u16*)((char*)hidsh + swz(16*mf + 4*kg + r, col*2, 768)) = f2bf(v);
      }
    }
  }
  __syncthreads();

  // gemm2: [64,384]x[384,96], wave w -> rows 16w..16w+15
  f32x4 a2[6] = {};
  #pragma unroll
  for (int ks=0; ks<12; ++ks){
    s16x8 af = LDSF(hidsh, 16*w+ln, ks*32+8*kg, 768);
    #pragma unroll
    for (int nf=0; nf<6; ++nf){
      s16x8 bfr = *(const s16x8*)(w2t + (size_t)(16*nf+ln)*384 + ks*32+8*kg);
      a2[nf] = mfma16(af, bfr, a2[nf]);
    }
  }
  float gg[6], bbv[6];
  #pragma unroll
  for (int nf=0; nf<6; ++nf){
    int col = 16*nf + ln;
    float bias = b2[col];
    gg[nf] = g1[col]; bbv[nf] = be1[col];
    #pragma unroll
    for (int r=0; r<4; ++r) a2[nf][r] += bias;
  }
  #pragma unroll
  for (int r=0; r<4; ++r){
    float s=0.f, sq=0.f;
    #pragma unroll
    for (int nf=0; nf<6; ++nf){ float v=a2[nf][r]; s+=v; sq+=v*v; }
    #pragma unroll
    for (int m=8; m; m>>=1){ s += __shfl_xor(s,m); sq += __shfl_xor(sq,m); }
    float mean = s*(1.f/96.f);
    float var  = sq*(1.f/96.f) - mean*mean;
    float rstd = rsqrtf(var + 1e-5f);
    int trow = 16*w + 4*kg + r;
    #pragma unroll
    for (int nf=0; nf<6; ++nf){
      float o = (a2[nf][r]-mean)*rstd*gg[nf] + bbv[nf];
      *(u16*)((char*)comb + swz(trow, (16*nf+ln)*2, 256)) = f2bf(o);
    }
  }
  __syncthreads();
  // coalesced x1 store
  for (int i=tid; i<64*12; i+=256){
    int l = i/12, sg = i%12;
    s16x8 v = *(const s16x8*)((const char*)comb + swz(l, sg*16, 256));
    int n = (ty*8+(l>>3))*192 + tx*8 + (l&7);
    *(s16x8*)(x1 + ((size_t)b*NTOK + n)*96 + sg*8) = v;
  }
}

// ---------------- K2: k,v (transposed) -> exp -> ctx accumulation ----------------
__global__ __launch_bounds__(256,2) void k2(
    const u16* __restrict__ x1, const u16* __restrict__ wkt, const u16* __restrict__ wvt,
    float* __restrict__ ctx_un)
{
  __shared__ u16 ekt[96*128];    // [d][token], stride 256B swz
  __shared__ u16 vt[112*128];    // [e][token] + ones row 96, stride 256B swz
  const int tid = threadIdx.x, w = tid>>6, lane = tid&63, kg = lane>>4, ln = lane&15;
  const int b = blockIdx.x>>5, chunk = blockIdx.x&31;
  const size_t tb0 = (size_t)b*NTOK + chunk*1152;

  for (int i=tid; i<16*128; i+=256){
    int rr = 96 + i/128, t = i%128;
    *(u16*)((char*)vt + swz(rr, t*2, 256)) = (rr==96) ? (u16)0x3f80 : (u16)0;
  }
  __syncthreads();
  const int tmi[20] = {0,0,1,1,1,2,2,3,3,4,4,4,5,5, 0,1,2,3,4,5};
  const int tni[20] = {0,1,0,1,2,1,2,3,4,3,4,5,4,5, 6,6,6,6,6,6};
  f32x4 ctx[20] = {};

  for (int it=0; it<9; ++it){
    // k^T, v^T: D[d][token] = Wt[d][:] . x[token][:]; x fragments direct from global
    f32x4 ka[6][2] = {};
    f32x4 va[6][2] = {};
    #pragma unroll
    for (int ks=0; ks<3; ++ks){
      s16x8 xb[2];
      #pragma unroll
      for (int tf=0; tf<2; ++tf)
        xb[tf] = *(const s16x8*)(x1 + (tb0 + it*128 + 16*(2*w+tf)+ln)*96 + ks*32+8*kg);
      #pragma unroll
      for (int mf=0; mf<6; ++mf){
        s16x8 ak = *(const s16x8*)(wkt + (size_t)(16*mf+ln)*96 + ks*32+8*kg);
        s16x8 av = *(const s16x8*)(wvt + (size_t)(16*mf+ln)*96 + ks*32+8*kg);
        #pragma unroll
        for (int tf=0; tf<2; ++tf){
          ka[mf][tf] = mfma16(ak, xb[tf], ka[mf][tf]);
          va[mf][tf] = mfma16(av, xb[tf], va[mf][tf]);
        }
      }
    }
    // exp (max-free: |k| < ~1 since x1 is LN'd, weights ~0.02); stage own-wave columns
    #pragma unroll
    for (int mf=0; mf<6; ++mf){
      #pragma unroll
      for (int tf=0; tf<2; ++tf){
        #pragma unroll
        for (int r=0; r<4; ++r){
          int d = 16*mf + 4*kg + r;
          int tok = 16*(2*w+tf) + ln;
          *(u16*)((char*)ekt + swz(d, tok*2, 256)) = f2bf(__expf(ka[mf][tf][r]));
          *(u16*)((char*)vt  + swz(d, tok*2, 256)) = f2bf(va[mf][tf][r]);
        }
      }
    }
    // ctx += exp_k^T @ v over this wave's 32 tokens (all LDS traffic is wave-local)
    s16x8 ea[6];
    #pragma unroll
    for (int mi=0; mi<6; ++mi) ea[mi] = LDSF(ekt, 16*mi+ln, 32*w+8*kg, 256);
    #pragma unroll
    for (int t=0; t<20; ++t){
      s16x8 vb = LDSF(vt, 16*tni[t]+ln, 32*w+8*kg, 256);
      ctx[t] = mfma16(ea[tmi[t]], vb, ctx[t]);
    }
  }
  // flush in-band entries + ksum
  #pragma unroll
  for (int t=0; t<20; ++t){
    #pragma unroll
    for (int r=0; r<4; ++r){
      int d = 16*tmi[t] + 4*kg + r;
      if (tni[t]==6){
        if (ln==0) atomicAdd(&ctx_un[(b*96+d)*112 + 96], ctx[t][r]);
      } else {
        int e = 16*tni[t] + ln;
        if (d/12 == e/12) atomicAdd(&ctx_un[(b*96+d)*112 + e], ctx[t][r]);
      }
    }
  }
}

// ---------------- K2c: normalize -> compact ctx [b][h][12][12] ----------------
__global__ void k2c(const float* __restrict__ ctx_un, float* __restrict__ ctxc){
  int i = blockIdx.x*256 + threadIdx.x;
  if (i < 8*1152){
    int b = i/1152, rr = i%1152, h = rr/144, de = rr%144, d = de/12, e = de%12;
    int dg = h*12+d, eg = h*12+e;
    ctxc[i] = ctx_un[(b*96+dg)*112 + eg] / ctx_un[(b*96+dg)*112 + 96];
  }
}

// ---------------- K3: q -> softmax -> ctx apply -> proj+res -> LN2 -> MLP2 -> out ----------------
__global__ __launch_bounds__(256,2) void k3(
    const u16* __restrict__ x1, const u16* __restrict__ wqt, const u16* __restrict__ pjt,
    const float* __restrict__ projb, const float* __restrict__ g2, const float* __restrict__ be2,
    const u16* __restrict__ m2w1t, const float* __restrict__ m2b1,
    const u16* __restrict__ m2w2t, const float* __restrict__ m2b2,
    const float* __restrict__ ctxc, float* __restrict__ out)
{
  __shared__ u16 bufA[128*128];   // stride 256B swz: q, then x2
  __shared__ u16 bufB[128*128];   // stride 256B swz: attn, then hidden chunk
  __shared__ float ctxsh[1152];
  __shared__ float rgbsh[3][128];
  const int tid = threadIdx.x, w = tid>>6, lane = tid&63, kg = lane>>4, ln = lane&15;
  const int bi = blockIdx.x, b = bi/288;
  const size_t t0 = (size_t)bi*128;
  const int n0 = (bi%288)*128;

  for (int i=tid; i<1152; i+=256) ctxsh[i] = ctxc[b*1152 + i];

  // q gemm (A fragments direct from global x1)
  f32x4 q[2][6] = {};
  #pragma unroll
  for (int ks=0; ks<3; ++ks){
    s16x8 a[2];
    #pragma unroll
    for (int mi=0; mi<2; ++mi)
      a[mi] = *(const s16x8*)(x1 + (t0 + 16*(2*w+mi)+ln)*96 + ks*32+8*kg);
    #pragma unroll
    for (int nf=0; nf<6; ++nf){
      s16x8 bfr = *(const s16x8*)(wqt + (size_t)(16*nf+ln)*96 + ks*32+8*kg);
      #pragma unroll
      for (int mi=0; mi<2; ++mi) q[mi][nf] = mfma16(a[mi], bfr, q[mi][nf]);
    }
  }
  #pragma unroll
  for (int mi=0; mi<2; ++mi)
    #pragma unroll
    for (int nf=0; nf<6; ++nf)
      #pragma unroll
      for (int r=0; r<4; ++r)
        *(u16*)((char*)bufA + swz(16*(2*w+mi)+4*kg+r, (16*nf+ln)*2, 256)) = f2bf(q[mi][nf][r]);
  __syncthreads();

  // softmax over head dim + apply ctx (cross-wave reads of bufA/ctxsh)
  const float scl = 0.28867513459481287f;  // 12^-0.5
  for (int i=tid; i<128*96; i+=256){
    int tok = i/96, j = i%96, h = j/12, e = j%12;
    float ex[12], ssum = 0.f;
    #pragma unroll
    for (int d=0; d<12; ++d){
      float qv = bf2f(*(const u16*)((const char*)bufA + swz(tok, (h*12+d)*2, 256)));
      ex[d] = __expf(qv); ssum += ex[d];
    }
    float inv = scl/ssum, a = 0.f;
    #pragma unroll
    for (int d=0; d<12; ++d) a += ex[d]*ctxsh[h*144 + d*12 + e];
    *(u16*)((char*)bufB + swz(tok, j*2, 256)) = f2bf(a*inv);
  }
  __syncthreads();

  // proj gemm (everything below is wave-local in LDS)
  f32x4 p[2][6] = {};
  #pragma unroll
  for (int ks=0; ks<3; ++ks){
    s16x8 a[2];
    #pragma unroll
    for (int mi=0; mi<2; ++mi) a[mi] = LDSF(bufB, 16*(2*w+mi)+ln, ks*32+8*kg, 256);
    #pragma unroll
    for (int nf=0; nf<6; ++nf){
      s16x8 bfr = *(const s16x8*)(pjt + (size_t)(16*nf+ln)*96 + ks*32+8*kg);
      #pragma unroll
      for (int mi=0; mi<2; ++mi) p[mi][nf] = mfma16(a[mi], bfr, p[mi][nf]);
    }
  }
  // bias + residual + LN2 -> x2 (bufA, own-wave rows)
  {
    float gg[6], bbv[6], pb[6];
    #pragma unroll
    for (int nf=0; nf<6; ++nf){
      int col = 16*nf + ln;
      pb[nf] = projb[col]; gg[nf] = g2[col]; bbv[nf] = be2[col];
    }
    #pragma unroll
    for (int mi=0; mi<2; ++mi){
      #pragma unroll
      for (int r=0; r<4; ++r){
        int trow = 16*(2*w+mi)+4*kg+r;
        float vv[6]; float s=0.f, sq=0.f;
        #pragma unroll
        for (int nf=0; nf<6; ++nf){
          float xv = bf2f(x1[(t0 + trow)*96 + 16*nf+ln]);
          float v = p[mi][nf][r] + pb[nf] + xv;
          vv[nf] = v; s += v; sq += v*v;
        }
        #pragma unroll
        for (int m=8; m; m>>=1){ s += __shfl_xor(s,m); sq += __shfl_xor(sq,m); }
        float mean = s*(1.f/96.f);
        float var  = sq*(1.f/96.f) - mean*mean;
        float rstd = rsqrtf(var + 1e-5f);
        #pragma unroll
        for (int nf=0; nf<6; ++nf){
          float o = (vv[nf]-mean)*rstd*gg[nf] + bbv[nf];
          *(u16*)((char*)bufA + swz(trow, (16*nf+ln)*2, 256)) = f2bf(o);
        }
      }
    }
  }

  // MLP2: 4 chunks of 96 hidden cols (all wave-local LDS; no barriers needed)
  f32x4 rgb[2] = {};
  for (int nc=0; nc<4; ++nc){
    f32x4 hh[2][6] = {};
    #pragma unroll
    for (int ks=0; ks<3; ++ks){
      s16x8 a[2];
      #pragma unroll
      for (int mi=0; mi<2; ++mi) a[mi] = LDSF(bufA, 16*(2*w+mi)+ln, ks*32+8*kg, 256);
      #pragma unroll
      for (int nf=0; nf<6; ++nf){
        s16x8 bfr = *(const s16x8*)(m2w1t + (size_t)(nc*96+16*nf+ln)*96 + ks*32+8*kg);
        #pragma unroll
        for (int mi=0; mi<2; ++mi) hh[mi][nf] = mfma16(a[mi], bfr, hh[mi][nf]);
      }
    }
    #pragma unroll
    for (int mi=0; mi<2; ++mi)
      #pragma unroll
      for (int nf=0; nf<6; ++nf){
        int col = 16*nf + ln;
        float bias = m2b1[nc*96+col];
        #pragma unroll
        for (int r=0; r<4; ++r){
          int trow = 16*(2*w+mi)+4*kg+r;
          *(u16*)((char*)bufB + swz(trow, col*2, 256)) = f2bf(gelu_(hh[mi][nf][r] + bias));
        }
      }
    #pragma unroll
    for (int ks=0; ks<3; ++ks){
      s16x8 bfr = *(const s16x8*)(m2w2t + (size_t)ln*384 + nc*96 + ks*32 + 8*kg);
      #pragma unroll
      for (int mi=0; mi<2; ++mi){
        s16x8 a = LDSF(bufB, 16*(2*w+mi)+ln, ks*32+8*kg, 256);
        rgb[mi] = mfma16(a, bfr, rgb[mi]);
      }
    }
  }
  if (ln < 3){
    float bias = m2b2[ln];
    #pragma unroll
    for (int mi=0; mi<2; ++mi)
      #pragma unroll
      for (int r=0; r<4; ++r){
        int trow = 16*(2*w+mi)+4*kg+r;
        float v = tanhf_(rgb[mi][r] + bias)*0.5f + 0.5f;
        v = fminf(fmaxf(v, 0.f), 1.f);
        rgbsh[ln][trow] = v;
      }
  }
  __syncthreads();
  for (int i=tid; i<384; i+=256){
    int ch = i>>7, t = i&127;
    out[((size_t)(b*3+ch))*NTOK + n0 + t] = rgbsh[ch][t];
  }
}

// ---------------- launch ----------------
extern "C" void kernel_launch(void* const* d_in, const int* in_sizes, int n_in,
                              void* d_out, int out_size, void* d_ws, size_t ws_size,
                              hipStream_t stream)
{
  (void)in_sizes; (void)n_in; (void)out_size; (void)ws_size;
  const float* feat  = (const float*)d_in[0];
  const float* m1w1  = (const float*)d_in[2];
  const float* m1b1  = (const float*)d_in[3];
  const float* m1w2  = (const float*)d_in[4];
  const float* m1b2  = (const float*)d_in[5];
  const float* n1g   = (const float*)d_in[6];
  const float* n1b   = (const float*)d_in[7];
  const float* qkvw  = (const float*)d_in[8];
  const float* projw = (const float*)d_in[9];
  const float* projb = (const float*)d_in[10];
  const float* n2g   = (const float*)d_in[11];
  const float* n2b   = (const float*)d_in[12];
  const float* m2w1  = (const float*)d_in[13];
  const float* m2b1  = (const float*)d_in[14];
  const float* m2w2  = (const float*)d_in[15];
  const float* m2b2  = (const float*)d_in[16];
  float* out = (float*)d_out;

  char* p = (char*)d_ws;
  auto bump = [&](size_t bytes)->char*{
    char* r = p;
    p += (bytes + 255) & ~(size_t)255;
    return r;
  };
  u16*  x1     = (u16*) bump((size_t)TTOT*96*2);
  u16*  featcl = (u16*) bump((size_t)8*96*96*96*2);
  u16*  ce     = (u16*) bump((size_t)NTOK*96*2);
  u16*  w1t    = (u16*) bump(73728*2);
  u16*  w2t    = (u16*) bump(36864*2);
  u16*  wqt    = (u16*) bump(9216*2);
  u16*  wkt    = (u16*) bump(9216*2);
  u16*  wvt    = (u16*) bump(9216*2);
  u16*  pjt    = (u16*) bump(9216*2);
  u16*  m2w1t  = (u16*) bump(36864*2);
  u16*  m2w2t  = (u16*) bump(6144*2);
  float* ctx_un= (float*)bump((size_t)8*96*112*4);
  float* ctxc  = (float*)bump((size_t)8*1152*4);

  hipLaunchKernelGGL(prep_w, dim3(744), dim3(256), 0, stream,
                     m1w1, m1w2, qkvw, projw, m2w1, m2w2,
                     w1t, w2t, wqt, wkt, wvt, pjt, m2w1t, m2w2t);
  hipLaunchKernelGGL(prep_feat, dim3(768), dim3(256), 0, stream, feat, featcl);
  hipLaunchKernelGGL(prep_ce, dim3(6912), dim3(256), 0, stream, ce);
  hipMemsetAsync(ctx_un, 0, (size_t)8*96*112*4, stream);
  hipLaunchKernelGGL(k1, dim3(4608), dim3(256), 0, stream,
                     featcl, ce, w1t, m1b1, w2t, m1b2, n1g, n1b, x1);
  hipLaunchKernelGGL(k2, dim3(256), dim3(256), 0, stream, x1, wkt, wvt, ctx_un);
  hipLaunchKernelGGL(k2c, dim3(36), dim3(256), 0, stream, ctx_un, ctxc);
  hipLaunchKernelGGL(k3, dim3(2304), dim3(256), 0, stream,
                     x1, wqt, pjt, projb, n2g, n2b, m2w1t, m2b1, m2w2t, m2b2, ctxc, out);
}

// Round 4
// 689.773 us; speedup vs baseline: 4.0576x; 1.0775x over previous
//
#include <hip/hip_runtime.h>
#include <math.h>

typedef unsigned short u16;
typedef unsigned int   u32;
typedef __bf16  bf16x8 __attribute__((ext_vector_type(8)));
typedef short   s16x8  __attribute__((ext_vector_type(8)));
typedef float   f32x4  __attribute__((ext_vector_type(4)));

#define NTOK 36864
#define TTOT (8*NTOK)

__device__ __forceinline__ f32x4 mfma16(s16x8 a, s16x8 b, f32x4 c){
  return __builtin_amdgcn_mfma_f32_16x16x32_bf16(
      __builtin_bit_cast(bf16x8, a), __builtin_bit_cast(bf16x8, b), c, 0, 0, 0);
}
// only valid for stride % 128 == 0 (XOR touches bits 4-6 -> bijective per 128B block)
__device__ __forceinline__ int swz(int row, int bc, int stride){
  return row*stride + (bc ^ ((row&7)<<4));
}
__device__ __forceinline__ u16 f2bf(float f){
  u32 u = __float_as_uint(f);
  return (u16)((u + 0x7fffu + ((u>>16)&1u)) >> 16);
}
__device__ __forceinline__ float bf2f(u16 h){ return __uint_as_float(((u32)h)<<16); }

// A&S 7.1.26 erf (|err|<1.5e-7)
__device__ __forceinline__ float gelu_(float x){
  float z = fabsf(x) * 0.70710678118654752f;
  float t = 1.0f/(1.0f + 0.3275911f*z);
  float poly = t*(0.254829592f + t*(-0.284496736f + t*(1.421413741f + t*(-1.453152027f + t*1.061405429f))));
  float e = __expf(-z*z);
  float erf = 1.0f - poly*e;
  erf = (x < 0.0f) ? -erf : erf;
  return 0.5f*x*(1.0f + erf);
}
__device__ __forceinline__ float tanhf_(float x){
  float e = __expf(2.0f*x);
  return 1.0f - 2.0f/(e + 1.0f);
}

#define LDSF(arr, row, kc, stride) (*(const s16x8*)((const char*)(arr) + swz((row),(kc)*2,(stride))))

// ---------------- prep: weights -> bf16 transposed ----------------
__global__ void prep_w(const float* __restrict__ w1, const float* __restrict__ w2,
                       const float* __restrict__ qkvw, const float* __restrict__ projw,
                       const float* __restrict__ m2w1, const float* __restrict__ m2w2,
                       u16* __restrict__ w1t, u16* __restrict__ w2t,
                       u16* __restrict__ wqt, u16* __restrict__ wkt, u16* __restrict__ wvt,
                       u16* __restrict__ pjt, u16* __restrict__ m2w1t, u16* __restrict__ m2w2t)
{
  int i = blockIdx.x*256 + threadIdx.x;
  if (i < 73728){ int n=i/192, k=i%192; w1t[i] = f2bf(w1[k*384+n]); return; }
  i -= 73728;
  if (i < 36864){ int n=i/384, k=i%384; w2t[i] = f2bf(w2[k*96+n]); return; }
  i -= 36864;
  if (i < 9216){ int n=i/96, k=i%96; wqt[i] = f2bf(qkvw[k*288+n]); return; }
  i -= 9216;
  if (i < 9216){ int n=i/96, k=i%96; wkt[i] = f2bf(qkvw[k*288+96+n]); return; }
  i -= 9216;
  if (i < 9216){ int n=i/96, k=i%96; wvt[i] = f2bf(qkvw[k*288+192+n]); return; }
  i -= 9216;
  if (i < 9216){ int n=i/96, k=i%96; pjt[i] = f2bf(projw[k*96+n]); return; }
  i -= 9216;
  if (i < 36864){ int n=i/96, k=i%96; m2w1t[i] = f2bf(m2w1[k*384+n]); return; }
  i -= 36864;
  if (i < 6144){ int n=i/384, k=i%384; m2w2t[i] = (n<3)? f2bf(m2w2[k*3+n]) : (u16)0; return; }
}

// ---------------- prep: features -> channel-last bf16 ----------------
__global__ void prep_feat(const float* __restrict__ feat, u16* __restrict__ featcl){
  __shared__ u16 t[96*100];
  const int tid = threadIdx.x;
  const int b = blockIdx.x/96, y = blockIdx.x%96;
  for (int i=tid; i<9216; i+=256){
    int c = i/96, x = i%96;
    t[c*100+x] = f2bf(feat[((size_t)(b*96+c)*96 + y)*96 + x]);
  }
  __syncthreads();
  for (int i=tid; i<9216; i+=256){
    int x = i/96, c = i%96;
    featcl[(((size_t)b*96 + y)*96 + x)*96 + c] = t[c*100+x];
  }
}

// ---------------- prep: coord encoding (scale==2 -> cs==1) ----------------
__global__ void prep_ce(u16* __restrict__ ce){
  int gid = blockIdx.x*256 + threadIdx.x;
  if (gid >= 36864*48) return;
  int n = gid/48, c2 = gid%48;
  int row = n/192, col = n%192;
  int fi = c2>>2, cs = c2&3;
  float coord = ((cs&1)==0) ? (float)row*(1.0f/191.0f) : (float)col*(1.0f/191.0f);
  float u = coord * (float)(1<<fi);
  u = u - 2.0f*floorf(u*0.5f);
  float ph = u * 3.14159265358979323846f;
  float s, c;
  __sincosf(ph, &s, &c);
  u32 pk = (u32)f2bf(s) | ((u32)f2bf(c)<<16);
  *(u32*)(ce + (size_t)n*96 + c2*2) = pk;
}

// ---------------- K1: upsample+ce -> MLP1 (split-K halves) -> LN1 -> x1(bf16) ----------------
__global__ __launch_bounds__(256,3) void k1(
    const u16* __restrict__ featcl, const u16* __restrict__ ce,
    const u16* __restrict__ w1t, const float* __restrict__ b1,
    const u16* __restrict__ w2t, const float* __restrict__ b2,
    const float* __restrict__ g1, const float* __restrict__ be1,
    u16* __restrict__ x1)
{
  __shared__ u16 comb[64*192];    // stride 384B swz; later stride 256B x1 staging
  __shared__ u16 hid[64*192];     // one 192-col half of hidden, stride 384B swz
  __shared__ float gwy[8][2]; __shared__ int giy[8][2];
  __shared__ float gwx[8][2]; __shared__ int gix[8][2];
  const int tid = threadIdx.x, w = tid>>6, lane = tid&63, kg = lane>>4, ln = lane&15;
  const int bi = blockIdx.x;
  const int b = bi/576, rem = bi%576, ty = rem/24, tx = rem%24;

  if (tid < 8){
    int row = ty*8 + tid;
    float fy = row*0.5f - 0.25f;
    int y0 = (int)floorf(fy); float dy = fy - (float)y0;
    giy[tid][0] = max(y0,0); giy[tid][1] = min(y0+1,95);
    gwy[tid][0] = 1.f-dy;    gwy[tid][1] = dy;
  } else if (tid < 16){
    int t = tid-8;
    int col = tx*8 + t;
    float fx = col*0.5f - 0.25f;
    int x0 = (int)floorf(fx); float dx = fx - (float)x0;
    gix[t][0] = max(x0,0); gix[t][1] = min(x0+1,95);
    gwx[t][0] = 1.f-dx;    gwx[t][1] = dx;
  }
  __syncthreads();

  // bilinear features -> comb[:, 0:96]
  const u16* fbase = featcl + (size_t)b*884736;
  for (int i=tid; i<64*48; i+=256){
    int l = i/48, c2 = i%48;
    int ly = l>>3, lx = l&7;
    float a0=0.f, a1=0.f;
    #pragma unroll
    for (int yy=0; yy<2; ++yy){
      #pragma unroll
      for (int xx=0; xx<2; ++xx){
        u32 u = *(const u32*)(fbase + ((size_t)(giy[ly][yy]*96 + gix[lx][xx]))*96 + c2*2);
        float wgt = gwy[ly][yy]*gwx[lx][xx];
        a0 += wgt * bf2f((u16)(u&0xffffu));
        a1 += wgt * bf2f((u16)(u>>16));
      }
    }
    u32 pk = (u32)f2bf(a0) | ((u32)f2bf(a1)<<16);
    *(u32*)((char*)comb + swz(l, c2*4, 384)) = pk;
  }
  // ce -> comb[:, 96:192]
  for (int i=tid; i<64*12; i+=256){
    int l = i/12, sg = i%12;
    int n = (ty*8+(l>>3))*192 + tx*8 + (l&7);
    *(s16x8*)((char*)comb + swz(l, 192 + sg*16, 384)) = *(const s16x8*)(ce + (size_t)n*96 + sg*8);
  }
  __syncthreads();

  // MLP1 in two hidden halves of 192 cols; a2 accumulates gemm2 across halves
  f32x4 a2[6] = {};
  for (int h=0; h<2; ++h){
    // gemm1 half: wave w -> local cols 48w .. 48w+47
    f32x4 acc[4][3] = {};
    #pragma unroll
    for (int ks=0; ks<6; ++ks){
      s16x8 af[4];
      #pragma unroll
      for (int mf=0; mf<4; ++mf) af[mf] = LDSF(comb, 16*mf+ln, ks*32+8*kg, 384);
      #pragma unroll
      for (int nf=0; nf<3; ++nf){
        s16x8 bfr = *(const s16x8*)(w1t + (size_t)(192*h+48*w+16*nf+ln)*192 + ks*32+8*kg);
        #pragma unroll
        for (int mf=0; mf<4; ++mf) acc[mf][nf] = mfma16(af[mf], bfr, acc[mf][nf]);
      }
    }
    if (h==1) __syncthreads();   // prev-half gemm2 readers done before overwrite
    // gelu -> hid (local col = 48w+16nf+ln)
    #pragma unroll
    for (int nf=0; nf<3; ++nf){
      int lcol = 48*w + 16*nf + ln;
      float bias = b1[192*h + lcol];
      #pragma unroll
      for (int mf=0; mf<4; ++mf){
        #pragma unroll
        for (int r=0; r<4; ++r){
          float v = gelu_(acc[mf][nf][r] + bias);
          *(u16*)((char*)hid + swz(16*mf + 4*kg + r, lcol*2, 384)) = f2bf(v);
        }
      }
    }
    __syncthreads();
    // gemm2 partial: wave w -> token rows 16w..16w+15, k = 192h..192h+191
    #pragma unroll
    for (int ks=0; ks<6; ++ks){
      s16x8 af = LDSF(hid, 16*w+ln, ks*32+8*kg, 384);
      #pragma unroll
      for (int nf=0; nf<6; ++nf){
        s16x8 bfr = *(const s16x8*)(w2t + (size_t)(16*nf+ln)*384 + 192*h + ks*32+8*kg);
        a2[nf] = mfma16(af, bfr, a2[nf]);
      }
    }
    if (h==0) __syncthreads();   // gemm2 reads done before next-half store
  }

  float gg[6], bbv[6];
  #pragma unroll
  for (int nf=0; nf<6; ++nf){
    int col = 16*nf + ln;
    float bias = b2[col];
    gg[nf] = g1[col]; bbv[nf] = be1[col];
    #pragma unroll
    for (int r=0; r<4; ++r) a2[nf][r] += bias;
  }
  __syncthreads();   // all comb (gemm1 A) reads complete before LN overwrites comb
  #pragma unroll
  for (int r=0; r<4; ++r){
    float s=0.f, sq=0.f;
    #pragma unroll
    for (int nf=0; nf<6; ++nf){ float v=a2[nf][r]; s+=v; sq+=v*v; }
    #pragma unroll
    for (int m=8; m; m>>=1){ s += __shfl_xor(s,m); sq += __shfl_xor(sq,m); }
    float mean = s*(1.f/96.f);
    float var  = sq*(1.f/96.f) - mean*mean;
    float rstd = rsqrtf(var + 1e-5f);
    int trow = 16*w + 4*kg + r;
    #pragma unroll
    for (int nf=0; nf<6; ++nf){
      float o = (a2[nf][r]-mean)*rstd*gg[nf] + bbv[nf];
      *(u16*)((char*)comb + swz(trow, (16*nf+ln)*2, 256)) = f2bf(o);
    }
  }
  __syncthreads();
  // coalesced x1 store
  for (int i=tid; i<64*12; i+=256){
    int l = i/12, sg = i%12;
    s16x8 v = *(const s16x8*)((const char*)comb + swz(l, sg*16, 256));
    int n = (ty*8+(l>>3))*192 + tx*8 + (l&7);
    *(s16x8*)(x1 + ((size_t)b*NTOK + n)*96 + sg*8) = v;
  }
}

// ---------------- K2: k,v (transposed) -> exp -> ctx accumulation ----------------
__global__ __launch_bounds__(256,2) void k2(
    const u16* __restrict__ x1, const u16* __restrict__ wkt, const u16* __restrict__ wvt,
    float* __restrict__ ctx_un)
{
  __shared__ u16 ekt[96*128];    // [d][token], stride 256B swz
  __shared__ u16 vt[112*128];    // [e][token] + ones row 96, stride 256B swz
  const int tid = threadIdx.x, w = tid>>6, lane = tid&63, kg = lane>>4, ln = lane&15;
  const int b = blockIdx.x/72, chunk = blockIdx.x%72;
  const size_t tb0 = (size_t)b*NTOK + chunk*512;

  for (int i=tid; i<16*128; i+=256){
    int rr = 96 + i/128, t = i%128;
    *(u16*)((char*)vt + swz(rr, t*2, 256)) = (rr==96) ? (u16)0x3f80 : (u16)0;
  }
  __syncthreads();
  const int tmi[20] = {0,0,1,1,1,2,2,3,3,4,4,4,5,5, 0,1,2,3,4,5};
  const int tni[20] = {0,1,0,1,2,1,2,3,4,3,4,5,4,5, 6,6,6,6,6,6};
  f32x4 ctx[20] = {};

  for (int it=0; it<4; ++it){
    f32x4 ka[6][2] = {};
    f32x4 va[6][2] = {};
    #pragma unroll
    for (int ks=0; ks<3; ++ks){
      s16x8 xb[2];
      #pragma unroll
      for (int tf=0; tf<2; ++tf)
        xb[tf] = *(const s16x8*)(x1 + (tb0 + it*128 + 16*(2*w+tf)+ln)*96 + ks*32+8*kg);
      #pragma unroll
      for (int mf=0; mf<6; ++mf){
        s16x8 ak = *(const s16x8*)(wkt + (size_t)(16*mf+ln)*96 + ks*32+8*kg);
        s16x8 av = *(const s16x8*)(wvt + (size_t)(16*mf+ln)*96 + ks*32+8*kg);
        #pragma unroll
        for (int tf=0; tf<2; ++tf){
          ka[mf][tf] = mfma16(ak, xb[tf], ka[mf][tf]);
          va[mf][tf] = mfma16(av, xb[tf], va[mf][tf]);
        }
      }
    }
    // exp (max-free: |k| < ~1, x1 LN'd + 0.02-scale weights); stage own-wave columns
    #pragma unroll
    for (int mf=0; mf<6; ++mf){
      #pragma unroll
      for (int tf=0; tf<2; ++tf){
        #pragma unroll
        for (int r=0; r<4; ++r){
          int d = 16*mf + 4*kg + r;
          int tok = 16*(2*w+tf) + ln;
          *(u16*)((char*)ekt + swz(d, tok*2, 256)) = f2bf(__expf(ka[mf][tf][r]));
          *(u16*)((char*)vt  + swz(d, tok*2, 256)) = f2bf(va[mf][tf][r]);
        }
      }
    }
    // ctx += exp_k^T @ v over this wave's 32 tokens (wave-local LDS)
    s16x8 ea[6];
    #pragma unroll
    for (int mi=0; mi<6; ++mi) ea[mi] = LDSF(ekt, 16*mi+ln, 32*w+8*kg, 256);
    #pragma unroll
    for (int t=0; t<20; ++t){
      s16x8 vb = LDSF(vt, 16*tni[t]+ln, 32*w+8*kg, 256);
      ctx[t] = mfma16(ea[tmi[t]], vb, ctx[t]);
    }
  }
  // flush in-band entries + ksum
  #pragma unroll
  for (int t=0; t<20; ++t){
    #pragma unroll
    for (int r=0; r<4; ++r){
      int d = 16*tmi[t] + 4*kg + r;
      if (tni[t]==6){
        if (ln==0) atomicAdd(&ctx_un[(b*96+d)*112 + 96], ctx[t][r]);
      } else {
        int e = 16*tni[t] + ln;
        if (d/12 == e/12) atomicAdd(&ctx_un[(b*96+d)*112 + e], ctx[t][r]);
      }
    }
  }
}

// ---------------- K2c: normalize -> compact ctx [b][h][12][12] ----------------
__global__ void k2c(const float* __restrict__ ctx_un, float* __restrict__ ctxc){
  int i = blockIdx.x*256 + threadIdx.x;
  if (i < 8*1152){
    int b = i/1152, rr = i%1152, h = rr/144, de = rr%144, d = de/12, e = de%12;
    int dg = h*12+d, eg = h*12+e;
    ctxc[i] = ctx_un[(b*96+dg)*112 + eg] / ctx_un[(b*96+dg)*112 + 96];
  }
}

// ---------------- K3: q -> softmax -> ctx apply -> proj+res -> LN2 -> MLP2 -> out ----------------
__global__ __launch_bounds__(256,2) void k3(
    const u16* __restrict__ x1, const u16* __restrict__ wqt, const u16* __restrict__ pjt,
    const float* __restrict__ projb, const float* __restrict__ g2, const float* __restrict__ be2,
    const u16* __restrict__ m2w1t, const float* __restrict__ m2b1,
    const u16* __restrict__ m2w2t, const float* __restrict__ m2b2,
    const float* __restrict__ ctxc, float* __restrict__ out)
{
  __shared__ u16 bufA[128*128];   // stride 256B swz: q, then x2
  __shared__ u16 bufB[128*128];   // stride 256B swz: attn, then hidden chunk
  __shared__ float ctxsh[8*145];  // padded: bank(145h%32) distinct per h
  __shared__ float rgbsh[3][128];
  const int tid = threadIdx.x, w = tid>>6, lane = tid&63, kg = lane>>4, ln = lane&15;
  const int bi = blockIdx.x, b = bi/288;
  const size_t t0 = (size_t)bi*128;
  const int n0 = (bi%288)*128;

  for (int i=tid; i<1152; i+=256){
    int h = i/144, rem = i%144;
    ctxsh[h*145 + rem] = ctxc[b*1152 + i];
  }

  // q gemm (A fragments direct from global x1)
  f32x4 q[2][6] = {};
  #pragma unroll
  for (int ks=0; ks<3; ++ks){
    s16x8 a[2];
    #pragma unroll
    for (int mi=0; mi<2; ++mi)
      a[mi] = *(const s16x8*)(x1 + (t0 + 16*(2*w+mi)+ln)*96 + ks*32+8*kg);
    #pragma unroll
    for (int nf=0; nf<6; ++nf){
      s16x8 bfr = *(const s16x8*)(wqt + (size_t)(16*nf+ln)*96 + ks*32+8*kg);
      #pragma unroll
      for (int mi=0; mi<2; ++mi) q[mi][nf] = mfma16(a[mi], bfr, q[mi][nf]);
    }
  }
  #pragma unroll
  for (int mi=0; mi<2; ++mi)
    #pragma unroll
    for (int nf=0; nf<6; ++nf)
      #pragma unroll
      for (int r=0; r<4; ++r)
        *(u16*)((char*)bufA + swz(16*(2*w+mi)+4*kg+r, (16*nf+ln)*2, 256)) = f2bf(q[mi][nf][r]);
  __syncthreads();

  // softmax over head dim + apply ctx: one (token,head) per thread iter
  const float scl = 0.28867513459481287f;  // 12^-0.5
  for (int p=tid; p<128*8; p+=256){
    int tok = p>>3, h = p&7;
    const float* cb = &ctxsh[h*145];
    float ex[12], ssum = 0.f;
    #pragma unroll
    for (int d=0; d<12; ++d){
      float qv = bf2f(*(const u16*)((const char*)bufA + swz(tok, (h*12+d)*2, 256)));
      ex[d] = __expf(qv); ssum += ex[d];
    }
    float inv = scl/ssum;
    #pragma unroll
    for (int e=0; e<12; ++e){
      float a = 0.f;
      #pragma unroll
      for (int d=0; d<12; ++d) a += ex[d]*cb[d*12+e];
      *(u16*)((char*)bufB + swz(tok, (h*12+e)*2, 256)) = f2bf(a*inv);
    }
  }
  __syncthreads();

  // proj gemm
  f32x4 p[2][6] = {};
  #pragma unroll
  for (int ks=0; ks<3; ++ks){
    s16x8 a[2];
    #pragma unroll
    for (int mi=0; mi<2; ++mi) a[mi] = LDSF(bufB, 16*(2*w+mi)+ln, ks*32+8*kg, 256);
    #pragma unroll
    for (int nf=0; nf<6; ++nf){
      s16x8 bfr = *(const s16x8*)(pjt + (size_t)(16*nf+ln)*96 + ks*32+8*kg);
      #pragma unroll
      for (int mi=0; mi<2; ++mi) p[mi][nf] = mfma16(a[mi], bfr, p[mi][nf]);
    }
  }
  // bias + residual + LN2 -> x2 (bufA, own-wave rows)
  {
    float gg[6], bbv[6], pb[6];
    #pragma unroll
    for (int nf=0; nf<6; ++nf){
      int col = 16*nf + ln;
      pb[nf] = projb[col]; gg[nf] = g2[col]; bbv[nf] = be2[col];
    }
    #pragma unroll
    for (int mi=0; mi<2; ++mi){
      #pragma unroll
      for (int r=0; r<4; ++r){
        int trow = 16*(2*w+mi)+4*kg+r;
        float vv[6]; float s=0.f, sq=0.f;
        #pragma unroll
        for (int nf=0; nf<6; ++nf){
          float xv = bf2f(x1[(t0 + trow)*96 + 16*nf+ln]);
          float v = p[mi][nf][r] + pb[nf] + xv;
          vv[nf] = v; s += v; sq += v*v;
        }
        #pragma unroll
        for (int m=8; m; m>>=1){ s += __shfl_xor(s,m); sq += __shfl_xor(sq,m); }
        float mean = s*(1.f/96.f);
        float var  = sq*(1.f/96.f) - mean*mean;
        float rstd = rsqrtf(var + 1e-5f);
        #pragma unroll
        for (int nf=0; nf<6; ++nf){
          float o = (vv[nf]-mean)*rstd*gg[nf] + bbv[nf];
          *(u16*)((char*)bufA + swz(trow, (16*nf+ln)*2, 256)) = f2bf(o);
        }
      }
    }
  }

  // MLP2: 4 chunks of 96 hidden cols (wave-local LDS; no barriers)
  f32x4 rgb[2] = {};
  for (int nc=0; nc<4; ++nc){
    f32x4 hh[2][6] = {};
    #pragma unroll
    for (int ks=0; ks<3; ++ks){
      s16x8 a[2];
      #pragma unroll
      for (int mi=0; mi<2; ++mi) a[mi] = LDSF(bufA, 16*(2*w+mi)+ln, ks*32+8*kg, 256);
      #pragma unroll
      for (int nf=0; nf<6; ++nf){
        s16x8 bfr = *(const s16x8*)(m2w1t + (size_t)(nc*96+16*nf+ln)*96 + ks*32+8*kg);
        #pragma unroll
        for (int mi=0; mi<2; ++mi) hh[mi][nf] = mfma16(a[mi], bfr, hh[mi][nf]);
      }
    }
    #pragma unroll
    for (int mi=0; mi<2; ++mi)
      #pragma unroll
      for (int nf=0; nf<6; ++nf){
        int col = 16*nf + ln;
        float bias = m2b1[nc*96+col];
        #pragma unroll
        for (int r=0; r<4; ++r){
          int trow = 16*(2*w+mi)+4*kg+r;
          *(u16*)((char*)bufB + swz(trow, col*2, 256)) = f2bf(gelu_(hh[mi][nf][r] + bias));
        }
      }
    #pragma unroll
    for (int ks=0; ks<3; ++ks){
      s16x8 bfr = *(const s16x8*)(m2w2t + (size_t)ln*384 + nc*96 + ks*32 + 8*kg);
      #pragma unroll
      for (int mi=0; mi<2; ++mi){
        s16x8 a = LDSF(bufB, 16*(2*w+mi)+ln, ks*32+8*kg, 256);
        rgb[mi] = mfma16(a, bfr, rgb[mi]);
      }
    }
  }
  if (ln < 3){
    float bias = m2b2[ln];
    #pragma unroll
    for (int mi=0; mi<2; ++mi)
      #pragma unroll
      for (int r=0; r<4; ++r){
        int trow = 16*(2*w+mi)+4*kg+r;
        float v = tanhf_(rgb[mi][r] + bias)*0.5f + 0.5f;
        v = fminf(fmaxf(v, 0.f), 1.f);
        rgbsh[ln][trow] = v;
      }
  }
  __syncthreads();
  for (int i=tid; i<384; i+=256){
    int ch = i>>7, t = i&127;
    out[((size_t)(b*3+ch))*NTOK + n0 + t] = rgbsh[ch][t];
  }
}

// ---------------- launch ----------------
extern "C" void kernel_launch(void* const* d_in, const int* in_sizes, int n_in,
                              void* d_out, int out_size, void* d_ws, size_t ws_size,
                              hipStream_t stream)
{
  (void)in_sizes; (void)n_in; (void)out_size; (void)ws_size;
  const float* feat  = (const float*)d_in[0];
  const float* m1w1  = (const float*)d_in[2];
  const float* m1b1  = (const float*)d_in[3];
  const float* m1w2  = (const float*)d_in[4];
  const float* m1b2  = (const float*)d_in[5];
  const float* n1g   = (const float*)d_in[6];
  const float* n1b   = (const float*)d_in[7];
  const float* qkvw  = (const float*)d_in[8];
  const float* projw = (const float*)d_in[9];
  const float* projb = (const float*)d_in[10];
  const float* n2g   = (const float*)d_in[11];
  const float* n2b   = (const float*)d_in[12];
  const float* m2w1  = (const float*)d_in[13];
  const float* m2b1  = (const float*)d_in[14];
  const float* m2w2  = (const float*)d_in[15];
  const float* m2b2  = (const float*)d_in[16];
  float* out = (float*)d_out;

  char* p = (char*)d_ws;
  auto bump = [&](size_t bytes)->char*{
    char* r = p;
    p += (bytes + 255) & ~(size_t)255;
    return r;
  };
  u16*  x1     = (u16*) bump((size_t)TTOT*96*2);
  u16*  featcl = (u16*) bump((size_t)8*96*96*96*2);
  u16*  ce     = (u16*) bump((size_t)NTOK*96*2);
  u16*  w1t    = (u16*) bump(73728*2);
  u16*  w2t    = (u16*) bump(36864*2);
  u16*  wqt    = (u16*) bump(9216*2);
  u16*  wkt    = (u16*) bump(9216*2);
  u16*  wvt    = (u16*) bump(9216*2);
  u16*  pjt    = (u16*) bump(9216*2);
  u16*  m2w1t  = (u16*) bump(36864*2);
  u16*  m2w2t  = (u16*) bump(6144*2);
  float* ctx_un= (float*)bump((size_t)8*96*112*4);
  float* ctxc  = (float*)bump((size_t)8*1152*4);

  hipLaunchKernelGGL(prep_w, dim3(744), dim3(256), 0, stream,
                     m1w1, m1w2, qkvw, projw, m2w1, m2w2,
                     w1t, w2t, wqt, wkt, wvt, pjt, m2w1t, m2w2t);
  hipLaunchKernelGGL(prep_feat, dim3(768), dim3(256), 0, stream, feat, featcl);
  hipLaunchKernelGGL(prep_ce, dim3(6912), dim3(256), 0, stream, ce);
  hipMemsetAsync(ctx_un, 0, (size_t)8*96*112*4, stream);
  hipLaunchKernelGGL(k1, dim3(4608), dim3(256), 0, stream,
                     featcl, ce, w1t, m1b1, w2t, m1b2, n1g, n1b, x1);
  hipLaunchKernelGGL(k2, dim3(576), dim3(256), 0, stream, x1, wkt, wvt, ctx_un);
  hipLaunchKernelGGL(k2c, dim3(36), dim3(256), 0, stream, ctx_un, ctxc);
  hipLaunchKernelGGL(k3, dim3(2304), dim3(256), 0, stream,
                     x1, wqt, pjt, projb, n2g, n2b, m2w1t, m2b1, m2w2t, m2b2, ctxc, out);
}